// Round 14
// baseline (266.028 us; speedup 1.0000x reference)
//
#include <hip/hip_runtime.h>
#include <hip/hip_bf16.h>

// GCN: N=100000 nodes, D=64, E=1600000 edges, 3 GCN steps, dropout p=0.3.
// Build (atomic-free counting sort, no global atomics):
//   P1 bucket_count -> P2 col_scan -> P3 scan_tot -> P4 bucket_scatter ->
//   P5 csr_finalize (per-bucket row sort + rowptr).
// SpMM: eighth-wave per node (8 lanes x uint4 = 8 packed bf16), 8 independent
//   edge chains per wave; 16-edge batches with clamped padding so a deg<=16
//   row needs a single load->gather round trip. __launch_bounds__(256,4)
//   raises the VGPR cap to 128 so the 16-deep batch stays in registers
//   (R13's default cap of 64 spilled to scratch: WRITE 37.5->106 MB).
//   f32 accumulate, fused out-RMW + dropout epilogue; u loaded nontemporal.

typedef __hip_bfloat16 bf16;
typedef float vfloat4 __attribute__((ext_vector_type(4)));

constexpr int   N_NODES  = 100000;
constexpr int   D        = 64;
constexpr int   E_EDGES  = 1600000;
constexpr int   ND       = N_NODES * D;
constexpr float P_DROP   = 0.3f;
constexpr float INV_KEEP = 1.0f / (1.0f - P_DROP);

constexpr int BROWS   = 512;                              // rows per bucket
constexpr int NB      = (N_NODES + BROWS - 1) / BROWS;    // 196 buckets
constexpr int TILE    = 2048;                              // edges per build block
constexpr int EPT     = TILE / 256;                        // 8 edges per thread
constexpr int BGRID   = (E_EDGES + TILE - 1) / TILE;       // 782 build blocks

// ---------- build phase ----------

__global__ void bucket_count(const int* __restrict__ rows, int* __restrict__ gcounts) {
    __shared__ int lc[NB];
    int tid = threadIdx.x;
    int base = blockIdx.x * TILE;
    for (int i = tid; i < NB; i += 256) lc[i] = 0;
    __syncthreads();
#pragma unroll
    for (int k = 0; k < EPT; ++k) {
        int e = base + k * 256 + tid;
        if (e < E_EDGES) atomicAdd(&lc[rows[e] >> 9], 1);
    }
    __syncthreads();
    int* g = gcounts + (size_t)blockIdx.x * NB;
    for (int i = tid; i < NB; i += 256) g[i] = lc[i];
}

__global__ void col_scan(int* __restrict__ gcounts, int* __restrict__ tot) {
    __shared__ int s[256];
    int b = blockIdx.x;
    int t = threadIdx.x;
    int v[4];
    int tsum = 0;
#pragma unroll
    for (int j = 0; j < 4; ++j) {
        int i = t * 4 + j;
        v[j] = (i < BGRID) ? gcounts[(size_t)i * NB + b] : 0;
        tsum += v[j];
    }
    s[t] = tsum;
    __syncthreads();
    for (int off = 1; off < 256; off <<= 1) {
        int x = (t >= off) ? s[t - off] : 0;
        __syncthreads();
        s[t] += x;
        __syncthreads();
    }
    int run = s[t] - tsum;
#pragma unroll
    for (int j = 0; j < 4; ++j) {
        int i = t * 4 + j;
        if (i < BGRID) {
            gcounts[(size_t)i * NB + b] = run;
            run += v[j];
        }
    }
    if (t == 255) tot[b] = s[255];
}

__global__ void scan_tot(const int* __restrict__ tot, int* __restrict__ base,
                         int* __restrict__ rowptr) {
    __shared__ int s[256];
    int t = threadIdx.x;
    int v = (t < NB) ? tot[t] : 0;
    s[t] = v;
    __syncthreads();
    for (int off = 1; off < 256; off <<= 1) {
        int x = (t >= off) ? s[t - off] : 0;
        __syncthreads();
        s[t] += x;
        __syncthreads();
    }
    if (t < NB) base[t] = s[t] - v;
    if (t == 255) {
        base[NB] = E_EDGES;
        rowptr[N_NODES] = E_EDGES;
    }
}

__global__ void bucket_scatter(const int* __restrict__ rows, const int* __restrict__ cols,
                               const float* __restrict__ vals,
                               const int* __restrict__ gcounts, const int* __restrict__ base,
                               int2* __restrict__ tmp) {
    __shared__ int lc[NB];
    __shared__ int gq[NB];
    int tid = threadIdx.x;
    int tbase = blockIdx.x * TILE;
    const int* g = gcounts + (size_t)blockIdx.x * NB;
    for (int i = tid; i < NB; i += 256) {
        lc[i] = 0;
        gq[i] = base[i] + g[i];
    }
    __syncthreads();
#pragma unroll
    for (int k = 0; k < EPT; ++k) {
        int e = tbase + k * 256 + tid;
        if (e < E_EDGES) {
            int r = rows[e];
            int b = r >> 9;
            int rank = atomicAdd(&lc[b], 1);
            tmp[gq[b] + rank] = make_int2(((r & (BROWS - 1)) << 17) | cols[e],
                                          __float_as_int(vals[e]));
        }
    }
}

__global__ void csr_finalize(const int* __restrict__ base, const int2* __restrict__ tmp,
                             int* __restrict__ rowptr, int2* __restrict__ sedge) {
    __shared__ int hist[BROWS];
    __shared__ int rcur[BROWS];
    __shared__ int s[256];
    int b = blockIdx.x;
    int tid = threadIdx.x;
    int seg_beg = base[b];
    int seg_end = base[b + 1];
    int rbase = b * BROWS;
    int rcount = min(BROWS, N_NODES - rbase);

    for (int i = tid; i < BROWS; i += 256) hist[i] = 0;
    __syncthreads();
    for (int i = seg_beg + tid; i < seg_end; i += 256)
        atomicAdd(&hist[tmp[i].x >> 17], 1);
    __syncthreads();

    int v0 = hist[2 * tid], v1 = hist[2 * tid + 1];
    int pair = v0 + v1;
    s[tid] = pair;
    __syncthreads();
    for (int off = 1; off < 256; off <<= 1) {
        int x = (tid >= off) ? s[tid - off] : 0;
        __syncthreads();
        s[tid] += x;
        __syncthreads();
    }
    int excl = s[tid] - pair;
    int p0 = seg_beg + excl;
    int p1 = p0 + v0;
    rcur[2 * tid] = p0;
    rcur[2 * tid + 1] = p1;
    if (2 * tid < rcount)     rowptr[rbase + 2 * tid] = p0;
    if (2 * tid + 1 < rcount) rowptr[rbase + 2 * tid + 1] = p1;
    __syncthreads();

    for (int i = seg_beg + tid; i < seg_end; i += 256) {
        int2 ev = tmp[i];
        int lr = ev.x >> 17;
        int cc = ev.x & 0x1FFFF;
        int p = atomicAdd(&rcur[lr], 1);
        sedge[p] = make_int2(cc, ev.y);
    }
}

// ---------- layer kernels ----------

__global__ void init_out_dropout(const float4* __restrict__ h, const float4* __restrict__ u,
                                 float4* __restrict__ out, bf16* __restrict__ t, int n4) {
    int i = blockIdx.x * blockDim.x + threadIdx.x;
    if (i >= n4) return;
    float4 c = h[i];
    float4 uu = u[i];
    out[i] = c;
    alignas(8) bf16 tb[4];
    tb[0] = __float2bfloat16((uu.x > P_DROP) ? c.x * INV_KEEP : 0.0f);
    tb[1] = __float2bfloat16((uu.y > P_DROP) ? c.y * INV_KEEP : 0.0f);
    tb[2] = __float2bfloat16((uu.z > P_DROP) ? c.z * INV_KEEP : 0.0f);
    tb[3] = __float2bfloat16((uu.w > P_DROP) ? c.w * INV_KEEP : 0.0f);
    *reinterpret_cast<uint2*>(&t[(size_t)i * 4]) = *reinterpret_cast<uint2*>(tb);
}

__device__ __forceinline__ unsigned short bf16_bits(float x) {
    bf16 b = __float2bfloat16(x);
    union { bf16 h; unsigned short u; } cv;
    cv.h = b;
    return cv.u;
}

// Eighth-wave (8 lanes) per node; lane handles features 8*lane..8*lane+7 via
// one uint4 gather (8 packed bf16). 16-edge batches: deg<=16 rows do a single
// dependent round trip. __launch_bounds__(256,4): VGPR cap 128, no spill.
template <bool HAS_NEXT>
__global__ __launch_bounds__(256, 4) void spmm_csr(
    const uint4* __restrict__ t4, const int* __restrict__ rowptr,
    const int2* __restrict__ sedge,
    const float* __restrict__ u_next, uint4* __restrict__ t4_next,
    float4* __restrict__ out4, float out_scale) {
    int node = blockIdx.x * 32 + (threadIdx.x >> 3);
    int lane = threadIdx.x & 7;
    if (node >= N_NODES) return;
    int beg = rowptr[node];
    int end = rowptr[node + 1];
    float s0 = 0.f, s1 = 0.f, s2 = 0.f, s3 = 0.f;
    float s4 = 0.f, s5 = 0.f, s6 = 0.f, s7 = 0.f;
    for (int i = beg; i < end; i += 16) {
        int2 e[16];
        uint4 p[16];
#pragma unroll
        for (int k = 0; k < 16; ++k) {
            int idx = (i + k < end) ? (i + k) : beg;
            e[k] = sedge[idx];
        }
#pragma unroll
        for (int k = 0; k < 16; ++k) p[k] = t4[(size_t)e[k].x * 8 + lane];
#pragma unroll
        for (int k = 0; k < 16; ++k) {
            float v = (i + k < end) ? __int_as_float(e[k].y) : 0.0f;
            s0 = fmaf(v, __int_as_float(p[k].x << 16), s0);
            s1 = fmaf(v, __int_as_float(p[k].x & 0xFFFF0000u), s1);
            s2 = fmaf(v, __int_as_float(p[k].y << 16), s2);
            s3 = fmaf(v, __int_as_float(p[k].y & 0xFFFF0000u), s3);
            s4 = fmaf(v, __int_as_float(p[k].z << 16), s4);
            s5 = fmaf(v, __int_as_float(p[k].z & 0xFFFF0000u), s5);
            s6 = fmaf(v, __int_as_float(p[k].w << 16), s6);
            s7 = fmaf(v, __int_as_float(p[k].w & 0xFFFF0000u), s7);
        }
    }
    size_t i16 = (size_t)node * 16 + 2 * lane;   // float4 granularity (2 per lane)
    float4 oa = out4[i16];
    float4 ob = out4[i16 + 1];
    oa.x = (oa.x + s0) * out_scale;
    oa.y = (oa.y + s1) * out_scale;
    oa.z = (oa.z + s2) * out_scale;
    oa.w = (oa.w + s3) * out_scale;
    ob.x = (ob.x + s4) * out_scale;
    ob.y = (ob.y + s5) * out_scale;
    ob.z = (ob.z + s6) * out_scale;
    ob.w = (ob.w + s7) * out_scale;
    out4[i16] = oa;
    out4[i16 + 1] = ob;
    if (HAS_NEXT) {
        const vfloat4* uv = (const vfloat4*)(u_next) + i16;
        vfloat4 ua = __builtin_nontemporal_load(uv);
        vfloat4 ub = __builtin_nontemporal_load(uv + 1);
        float d0 = (ua.x > P_DROP) ? s0 * INV_KEEP : 0.0f;
        float d1 = (ua.y > P_DROP) ? s1 * INV_KEEP : 0.0f;
        float d2 = (ua.z > P_DROP) ? s2 * INV_KEEP : 0.0f;
        float d3 = (ua.w > P_DROP) ? s3 * INV_KEEP : 0.0f;
        float d4 = (ub.x > P_DROP) ? s4 * INV_KEEP : 0.0f;
        float d5 = (ub.y > P_DROP) ? s5 * INV_KEEP : 0.0f;
        float d6 = (ub.z > P_DROP) ? s6 * INV_KEEP : 0.0f;
        float d7 = (ub.w > P_DROP) ? s7 * INV_KEEP : 0.0f;
        uint4 pk;
        pk.x = (unsigned int)bf16_bits(d0) | ((unsigned int)bf16_bits(d1) << 16);
        pk.y = (unsigned int)bf16_bits(d2) | ((unsigned int)bf16_bits(d3) << 16);
        pk.z = (unsigned int)bf16_bits(d4) | ((unsigned int)bf16_bits(d5) << 16);
        pk.w = (unsigned int)bf16_bits(d6) | ((unsigned int)bf16_bits(d7) << 16);
        t4_next[(size_t)node * 8 + lane] = pk;
    }
}

extern "C" void kernel_launch(void* const* d_in, const int* in_sizes, int n_in,
                              void* d_out, int out_size, void* d_ws, size_t ws_size,
                              hipStream_t stream) {
    const float* h    = (const float*)d_in[0];
    const float* vals = (const float*)d_in[1];
    const float* u    = (const float*)d_in[2];
    const int*   rows = (const int*)d_in[3];
    const int*   cols = (const int*)d_in[4];
    float* out = (float*)d_out;

    // workspace layout (tmp aliases T0+T1; tmp dead before init_out_dropout)
    bf16* T0      = (bf16*)d_ws;                  // [ND] bf16 (12.8 MB)
    bf16* T1      = T0 + ND;                      // [ND] bf16 (12.8 MB)
    int2* tmp     = (int2*)T0;                    // [E] bucket-major (alias, build only)
    int2* sedge   = (int2*)(T1 + ND);             // [E] row-sorted (col, f32 val)
    int*  rowptr  = (int*)(sedge + E_EDGES);      // [N+1]
    int*  gcounts = rowptr + (N_NODES + 1);       // [BGRID*NB]
    int*  tot     = gcounts + (size_t)BGRID * NB; // [NB]
    int*  base    = tot + NB;                     // [NB+1]

    const int n4 = ND / 4;
    dim3 blk(256);
    int gElem = (n4 + 255) / 256;
    int gNode = (N_NODES + 31) / 32;   // 32 eighth-waves (nodes) per 256-thread block

    // ---- build (atomic-free counting sort -> row-sorted CSR) ----
    bucket_count<<<BGRID, blk, 0, stream>>>(rows, gcounts);
    col_scan<<<NB, blk, 0, stream>>>(gcounts, tot);
    scan_tot<<<1, blk, 0, stream>>>(tot, base, rowptr);
    bucket_scatter<<<BGRID, blk, 0, stream>>>(rows, cols, vals, gcounts, base, tmp);
    csr_finalize<<<NB, blk, 0, stream>>>(base, tmp, rowptr, sedge);

    // ---- layer 0 prologue: out = h, T0 = dropout(h, u0) ----
    init_out_dropout<<<gElem, blk, 0, stream>>>((const float4*)h, (const float4*)u,
                                                (float4*)out, T0, n4);

    // ---- layers ----
    spmm_csr<true><<<gNode, blk, 0, stream>>>((const uint4*)T0, rowptr, sedge,
                                              u + (size_t)1 * ND,
                                              (uint4*)T1, (float4*)out, 1.0f);
    spmm_csr<true><<<gNode, blk, 0, stream>>>((const uint4*)T1, rowptr, sedge,
                                              u + (size_t)2 * ND,
                                              (uint4*)T0, (float4*)out, 1.0f);
    spmm_csr<false><<<gNode, blk, 0, stream>>>((const uint4*)T0, rowptr, sedge,
                                               nullptr, nullptr, (float4*)out, 0.25f);
}

// Round 15
// 185.737 us; speedup vs baseline: 1.4323x; 1.4323x over previous
//
#include <hip/hip_runtime.h>
#include <hip/hip_bf16.h>

// GCN: N=100000 nodes, D=64, E=1600000 edges, 3 GCN steps, dropout p=0.3.
// Build (atomic-free counting sort): bucket_count -> col_scan -> scan_tot ->
//   bucket_scatter -> csr_finalize (per-bucket row sort + rowptr).
// SpMM: eighth-wave per node (8 lanes x uint4 = 8 packed bf16), 8 independent
//   edge chains per wave, 8-edge batches; block stages its contiguous CSR edge
//   range (32 consecutive nodes) into LDS so each round trip starts from an
//   LDS read instead of a global load. f32 accumulate, fused epilogue.

typedef __hip_bfloat16 bf16;
typedef float vfloat4 __attribute__((ext_vector_type(4)));

constexpr int   N_NODES  = 100000;
constexpr int   D        = 64;
constexpr int   E_EDGES  = 1600000;
constexpr int   ND       = N_NODES * D;
constexpr float P_DROP   = 0.3f;
constexpr float INV_KEEP = 1.0f / (1.0f - P_DROP);

constexpr int BROWS   = 512;                              // rows per bucket
constexpr int NB      = (N_NODES + BROWS - 1) / BROWS;    // 196 buckets
constexpr int TILE    = 2048;                              // edges per build block
constexpr int EPT     = TILE / 256;                        // 8 edges per thread
constexpr int BGRID   = (E_EDGES + TILE - 1) / TILE;       // 782 build blocks

constexpr int NPB     = 32;                                // nodes per spmm block
constexpr int ECAP    = 2048;                              // staged edges (16 KB)

// ---------- build phase ----------

__global__ void bucket_count(const int* __restrict__ rows, int* __restrict__ gcounts) {
    __shared__ int lc[NB];
    int tid = threadIdx.x;
    int base = blockIdx.x * TILE;
    for (int i = tid; i < NB; i += 256) lc[i] = 0;
    __syncthreads();
#pragma unroll
    for (int k = 0; k < EPT; ++k) {
        int e = base + k * 256 + tid;
        if (e < E_EDGES) atomicAdd(&lc[rows[e] >> 9], 1);
    }
    __syncthreads();
    int* g = gcounts + (size_t)blockIdx.x * NB;
    for (int i = tid; i < NB; i += 256) g[i] = lc[i];
}

__global__ void col_scan(int* __restrict__ gcounts, int* __restrict__ tot) {
    __shared__ int s[256];
    int b = blockIdx.x;
    int t = threadIdx.x;
    int v[4];
    int tsum = 0;
#pragma unroll
    for (int j = 0; j < 4; ++j) {
        int i = t * 4 + j;
        v[j] = (i < BGRID) ? gcounts[(size_t)i * NB + b] : 0;
        tsum += v[j];
    }
    s[t] = tsum;
    __syncthreads();
    for (int off = 1; off < 256; off <<= 1) {
        int x = (t >= off) ? s[t - off] : 0;
        __syncthreads();
        s[t] += x;
        __syncthreads();
    }
    int run = s[t] - tsum;
#pragma unroll
    for (int j = 0; j < 4; ++j) {
        int i = t * 4 + j;
        if (i < BGRID) {
            gcounts[(size_t)i * NB + b] = run;
            run += v[j];
        }
    }
    if (t == 255) tot[b] = s[255];
}

__global__ void scan_tot(const int* __restrict__ tot, int* __restrict__ base,
                         int* __restrict__ rowptr) {
    __shared__ int s[256];
    int t = threadIdx.x;
    int v = (t < NB) ? tot[t] : 0;
    s[t] = v;
    __syncthreads();
    for (int off = 1; off < 256; off <<= 1) {
        int x = (t >= off) ? s[t - off] : 0;
        __syncthreads();
        s[t] += x;
        __syncthreads();
    }
    if (t < NB) base[t] = s[t] - v;
    if (t == 255) {
        base[NB] = E_EDGES;
        rowptr[N_NODES] = E_EDGES;
    }
}

__global__ void bucket_scatter(const int* __restrict__ rows, const int* __restrict__ cols,
                               const float* __restrict__ vals,
                               const int* __restrict__ gcounts, const int* __restrict__ base,
                               int2* __restrict__ tmp) {
    __shared__ int lc[NB];
    __shared__ int gq[NB];
    int tid = threadIdx.x;
    int tbase = blockIdx.x * TILE;
    const int* g = gcounts + (size_t)blockIdx.x * NB;
    for (int i = tid; i < NB; i += 256) {
        lc[i] = 0;
        gq[i] = base[i] + g[i];
    }
    __syncthreads();
#pragma unroll
    for (int k = 0; k < EPT; ++k) {
        int e = tbase + k * 256 + tid;
        if (e < E_EDGES) {
            int r = rows[e];
            int b = r >> 9;
            int rank = atomicAdd(&lc[b], 1);
            tmp[gq[b] + rank] = make_int2(((r & (BROWS - 1)) << 17) | cols[e],
                                          __float_as_int(vals[e]));
        }
    }
}

__global__ void csr_finalize(const int* __restrict__ base, const int2* __restrict__ tmp,
                             int* __restrict__ rowptr, int2* __restrict__ sedge) {
    __shared__ int hist[BROWS];
    __shared__ int rcur[BROWS];
    __shared__ int s[256];
    int b = blockIdx.x;
    int tid = threadIdx.x;
    int seg_beg = base[b];
    int seg_end = base[b + 1];
    int rbase = b * BROWS;
    int rcount = min(BROWS, N_NODES - rbase);

    for (int i = tid; i < BROWS; i += 256) hist[i] = 0;
    __syncthreads();
    for (int i = seg_beg + tid; i < seg_end; i += 256)
        atomicAdd(&hist[tmp[i].x >> 17], 1);
    __syncthreads();

    int v0 = hist[2 * tid], v1 = hist[2 * tid + 1];
    int pair = v0 + v1;
    s[tid] = pair;
    __syncthreads();
    for (int off = 1; off < 256; off <<= 1) {
        int x = (tid >= off) ? s[tid - off] : 0;
        __syncthreads();
        s[tid] += x;
        __syncthreads();
    }
    int excl = s[tid] - pair;
    int p0 = seg_beg + excl;
    int p1 = p0 + v0;
    rcur[2 * tid] = p0;
    rcur[2 * tid + 1] = p1;
    if (2 * tid < rcount)     rowptr[rbase + 2 * tid] = p0;
    if (2 * tid + 1 < rcount) rowptr[rbase + 2 * tid + 1] = p1;
    __syncthreads();

    for (int i = seg_beg + tid; i < seg_end; i += 256) {
        int2 ev = tmp[i];
        int lr = ev.x >> 17;
        int cc = ev.x & 0x1FFFF;
        int p = atomicAdd(&rcur[lr], 1);
        sedge[p] = make_int2(cc, ev.y);
    }
}

// ---------- layer kernels ----------

__global__ void init_out_dropout(const float4* __restrict__ h, const float4* __restrict__ u,
                                 float4* __restrict__ out, bf16* __restrict__ t, int n4) {
    int i = blockIdx.x * blockDim.x + threadIdx.x;
    if (i >= n4) return;
    float4 c = h[i];
    float4 uu = u[i];
    out[i] = c;
    alignas(8) bf16 tb[4];
    tb[0] = __float2bfloat16((uu.x > P_DROP) ? c.x * INV_KEEP : 0.0f);
    tb[1] = __float2bfloat16((uu.y > P_DROP) ? c.y * INV_KEEP : 0.0f);
    tb[2] = __float2bfloat16((uu.z > P_DROP) ? c.z * INV_KEEP : 0.0f);
    tb[3] = __float2bfloat16((uu.w > P_DROP) ? c.w * INV_KEEP : 0.0f);
    *reinterpret_cast<uint2*>(&t[(size_t)i * 4]) = *reinterpret_cast<uint2*>(tb);
}

__device__ __forceinline__ unsigned short bf16_bits(float x) {
    bf16 b = __float2bfloat16(x);
    union { bf16 h; unsigned short u; } cv;
    cv.h = b;
    return cv.u;
}

// Eighth-wave (8 lanes) per node; lane handles features 8*lane..8*lane+7 via
// one uint4 gather (8 packed bf16). Block = 32 consecutive nodes; the block's
// contiguous CSR edge range is staged into LDS so each dependent round trip
// starts with an LDS read (~120cy) instead of a global load (~200-600cy).
template <bool HAS_NEXT>
__global__ __launch_bounds__(256) void spmm_csr(
    const uint4* __restrict__ t4, const int* __restrict__ rowptr,
    const int2* __restrict__ sedge,
    const float* __restrict__ u_next, uint4* __restrict__ t4_next,
    float4* __restrict__ out4, float out_scale) {
    __shared__ int2 elds[ECAP];
    int tid = threadIdx.x;
    int nb0 = blockIdx.x * NPB;
    int ebeg = rowptr[nb0];
    int eend = rowptr[nb0 + NPB];
    int cnt = eend - ebeg;
    bool fast = (cnt <= ECAP);
    if (fast)
        for (int i = tid; i < cnt; i += 256) elds[i] = sedge[ebeg + i];
    __syncthreads();

    int node = nb0 + (tid >> 3);
    int lane = tid & 7;
    int beg = rowptr[node];
    int end = rowptr[node + 1];
    float s0 = 0.f, s1 = 0.f, s2 = 0.f, s3 = 0.f;
    float s4 = 0.f, s5 = 0.f, s6 = 0.f, s7 = 0.f;

    auto run = [&](auto ge) {
        for (int i = beg; i < end; i += 8) {
            int2 e[8];
            uint4 p[8];
#pragma unroll
            for (int k = 0; k < 8; ++k) {
                int j = (i + k < end) ? (i + k) : beg;
                e[k] = ge(j);
            }
#pragma unroll
            for (int k = 0; k < 8; ++k) p[k] = t4[(size_t)e[k].x * 8 + lane];
#pragma unroll
            for (int k = 0; k < 8; ++k) {
                float v = (i + k < end) ? __int_as_float(e[k].y) : 0.0f;
                s0 = fmaf(v, __int_as_float(p[k].x << 16), s0);
                s1 = fmaf(v, __int_as_float(p[k].x & 0xFFFF0000u), s1);
                s2 = fmaf(v, __int_as_float(p[k].y << 16), s2);
                s3 = fmaf(v, __int_as_float(p[k].y & 0xFFFF0000u), s3);
                s4 = fmaf(v, __int_as_float(p[k].z << 16), s4);
                s5 = fmaf(v, __int_as_float(p[k].z & 0xFFFF0000u), s5);
                s6 = fmaf(v, __int_as_float(p[k].w << 16), s6);
                s7 = fmaf(v, __int_as_float(p[k].w & 0xFFFF0000u), s7);
            }
        }
    };
    if (fast) run([&](int j) { return elds[j - ebeg]; });
    else      run([&](int j) { return sedge[j]; });

    size_t i16 = (size_t)node * 16 + 2 * lane;   // float4 granularity (2 per lane)
    float4 oa = out4[i16];
    float4 ob = out4[i16 + 1];
    oa.x = (oa.x + s0) * out_scale;
    oa.y = (oa.y + s1) * out_scale;
    oa.z = (oa.z + s2) * out_scale;
    oa.w = (oa.w + s3) * out_scale;
    ob.x = (ob.x + s4) * out_scale;
    ob.y = (ob.y + s5) * out_scale;
    ob.z = (ob.z + s6) * out_scale;
    ob.w = (ob.w + s7) * out_scale;
    out4[i16] = oa;
    out4[i16 + 1] = ob;
    if (HAS_NEXT) {
        const vfloat4* uv = (const vfloat4*)(u_next) + i16;
        vfloat4 ua = __builtin_nontemporal_load(uv);
        vfloat4 ub = __builtin_nontemporal_load(uv + 1);
        float d0 = (ua.x > P_DROP) ? s0 * INV_KEEP : 0.0f;
        float d1 = (ua.y > P_DROP) ? s1 * INV_KEEP : 0.0f;
        float d2 = (ua.z > P_DROP) ? s2 * INV_KEEP : 0.0f;
        float d3 = (ua.w > P_DROP) ? s3 * INV_KEEP : 0.0f;
        float d4 = (ub.x > P_DROP) ? s4 * INV_KEEP : 0.0f;
        float d5 = (ub.y > P_DROP) ? s5 * INV_KEEP : 0.0f;
        float d6 = (ub.z > P_DROP) ? s6 * INV_KEEP : 0.0f;
        float d7 = (ub.w > P_DROP) ? s7 * INV_KEEP : 0.0f;
        uint4 pk;
        pk.x = (unsigned int)bf16_bits(d0) | ((unsigned int)bf16_bits(d1) << 16);
        pk.y = (unsigned int)bf16_bits(d2) | ((unsigned int)bf16_bits(d3) << 16);
        pk.z = (unsigned int)bf16_bits(d4) | ((unsigned int)bf16_bits(d5) << 16);
        pk.w = (unsigned int)bf16_bits(d6) | ((unsigned int)bf16_bits(d7) << 16);
        t4_next[(size_t)node * 8 + lane] = pk;
    }
}

extern "C" void kernel_launch(void* const* d_in, const int* in_sizes, int n_in,
                              void* d_out, int out_size, void* d_ws, size_t ws_size,
                              hipStream_t stream) {
    const float* h    = (const float*)d_in[0];
    const float* vals = (const float*)d_in[1];
    const float* u    = (const float*)d_in[2];
    const int*   rows = (const int*)d_in[3];
    const int*   cols = (const int*)d_in[4];
    float* out = (float*)d_out;

    // workspace layout (tmp aliases T0+T1; tmp dead before init_out_dropout)
    bf16* T0      = (bf16*)d_ws;                  // [ND] bf16 (12.8 MB)
    bf16* T1      = T0 + ND;                      // [ND] bf16 (12.8 MB)
    int2* tmp     = (int2*)T0;                    // [E] bucket-major (alias, build only)
    int2* sedge   = (int2*)(T1 + ND);             // [E] row-sorted (col, f32 val)
    int*  rowptr  = (int*)(sedge + E_EDGES);      // [N+1]
    int*  gcounts = rowptr + (N_NODES + 1);       // [BGRID*NB]
    int*  tot     = gcounts + (size_t)BGRID * NB; // [NB]
    int*  base    = tot + NB;                     // [NB+1]

    const int n4 = ND / 4;
    dim3 blk(256);
    int gElem = (n4 + 255) / 256;
    int gNode = N_NODES / NPB;   // 3125 blocks, 32 nodes each (exact)

    // ---- build (atomic-free counting sort -> row-sorted CSR) ----
    bucket_count<<<BGRID, blk, 0, stream>>>(rows, gcounts);
    col_scan<<<NB, blk, 0, stream>>>(gcounts, tot);
    scan_tot<<<1, blk, 0, stream>>>(tot, base, rowptr);
    bucket_scatter<<<BGRID, blk, 0, stream>>>(rows, cols, vals, gcounts, base, tmp);
    csr_finalize<<<NB, blk, 0, stream>>>(base, tmp, rowptr, sedge);

    // ---- layer 0 prologue: out = h, T0 = dropout(h, u0) ----
    init_out_dropout<<<gElem, blk, 0, stream>>>((const float4*)h, (const float4*)u,
                                                (float4*)out, T0, n4);

    // ---- layers ----
    spmm_csr<true><<<gNode, blk, 0, stream>>>((const uint4*)T0, rowptr, sedge,
                                              u + (size_t)1 * ND,
                                              (uint4*)T1, (float4*)out, 1.0f);
    spmm_csr<true><<<gNode, blk, 0, stream>>>((const uint4*)T1, rowptr, sedge,
                                              u + (size_t)2 * ND,
                                              (uint4*)T0, (float4*)out, 1.0f);
    spmm_csr<false><<<gNode, blk, 0, stream>>>((const uint4*)T0, rowptr, sedge,
                                               nullptr, nullptr, (float4*)out, 0.25f);
}